// Round 9
// baseline (56.137 us; speedup 1.0000x reference)
//
#include <hip/hip_runtime.h>
#include <math.h>

// GptOssTopKRouter on MI355X — round 9: operand-swapped 3-term split-bf16 MFMA,
// no LDS staging, 4-way K-split for 4 waves/SIMD occupancy.
//
// logits^T = W[32,2880] @ X^T as 6 bf16 MFMA passes (X,W each trunc-split into
// hi+mid+lo bf16; passes hh,mh,lh,hm,mm,hl -> logit err ~2e-7, tie-safe for
// top-4 indices; round-8's 2-term split flipped a near-tie).
//
// Structure: X is the B operand — B-frag layout (col=lane&15=token,
// k=(lane>>4)*8+j) IS X's natural row-major layout: each lane loads 8
// consecutive fp32 of its token, splits to 3 bf16x8 IN REGISTERS. Zero LDS
// staging, zero barriers in the main loop. W is the A operand, pre-split and
// fragment-packed by wb_kernel (3 vers x 96 ks x 2 etiles x 512, 1.18 MB in
// d_ws, L2-resident; ks 90..95 zero-padded so all K-quarters run a uniform
// 24 steps; X addr clamped for pad steps).
// Block = 512 thr = 8 waves = 2 M-tiles x 4 K-quarters; grid 512 -> 2
// blocks/CU = 16 waves/CU = 4/SIMD (launch_bounds(512,4) caps VGPR at 128).
// Pipeline: 2-phase, reload-after-consume (X right after split, W right
// after its MFMAs) -> no register copies.

#define HIDDEN 2880
#define NE 32
#define TOPK 4
#define TPB 32            // tokens per block
#define KSLOTS 96         // padded k-steps (90 real + 6 zero)
#define VS (KSLOTS * 2 * 512)   // ver stride in wb: 98304 shorts

typedef __attribute__((ext_vector_type(8))) short bf16x8;
typedef __attribute__((ext_vector_type(4))) float f32x4;

#define MFMA(a, b, c) __builtin_amdgcn_mfma_f32_16x16x32_bf16((a), (b), (c), 0, 0, 0)

// Pre-kernel: W[32][2880] fp32 -> WB[3 ver][96 ks][2 et][512] bf16, exact
// A-fragment order: elem (l,j) = split_ver(W[et*16+(l&15)][ks*32+(l>>4)*8+j]);
// ks >= 90 slots are zero.
__global__ void wb_kernel(const float* __restrict__ w, unsigned short* __restrict__ wb) {
    int i = blockIdx.x * 256 + threadIdx.x;
    if (i >= 3 * VS) return;
    int j = i & 7;
    int t = i >> 3;
    int l = t & 63;  t >>= 6;
    int et = t & 1;  t >>= 1;
    int ks = t % KSLOTS;
    int ver = t / KSLOTS;
    unsigned short outv = 0;
    if (ks < 90) {
        int e = et * 16 + (l & 15);
        int k = ks * 32 + (l >> 4) * 8 + j;
        float v = w[e * HIDDEN + k];
        unsigned u = __float_as_uint(v);
        unsigned h = u >> 16;
        float r = v - __uint_as_float(u & 0xffff0000u);          // exact
        unsigned ur = __float_as_uint(r);
        unsigned m = ur >> 16;
        float r2 = r - __uint_as_float(ur & 0xffff0000u);        // exact
        unsigned lo = __float_as_uint(r2) >> 16;
        outv = (unsigned short)(ver == 0 ? h : (ver == 1 ? m : lo));
    }
    wb[i] = outv;
}

// split 8 consecutive fp32 -> 3 bf16x8 (hi, mid, lo), fully in-register
__device__ __forceinline__ void split24(float4 a, float4 b,
                                        bf16x8& H, bf16x8& M, bf16x8& L) {
    union { bf16x8 v; unsigned u[4]; } h, m, l;
    float f[8] = {a.x, a.y, a.z, a.w, b.x, b.y, b.z, b.w};
    unsigned hh[8], mm[8], ll[8];
#pragma unroll
    for (int i = 0; i < 8; ++i) {
        unsigned u = __float_as_uint(f[i]);
        hh[i] = u >> 16;
        float r = f[i] - __uint_as_float(u & 0xffff0000u);       // exact
        unsigned ur = __float_as_uint(r);
        mm[i] = ur >> 16;
        float r2 = r - __uint_as_float(ur & 0xffff0000u);        // exact
        ll[i] = __float_as_uint(r2) >> 16;
    }
#pragma unroll
    for (int i = 0; i < 4; ++i) {
        h.u[i] = hh[2 * i] | (hh[2 * i + 1] << 16);
        m.u[i] = mm[2 * i] | (mm[2 * i + 1] << 16);
        l.u[i] = ll[2 * i] | (ll[2 * i + 1] << 16);
    }
    H = h.v; M = m.v; L = l.v;
}

__global__ __launch_bounds__(512, 4)
void router_kernel(const float* __restrict__ x,
                   const unsigned short* __restrict__ wb,
                   const float* __restrict__ bias,
                   float* __restrict__ out_scores,
                   float* __restrict__ out_idx)
{
    __shared__ float part[4][TPB][36];    // 18.4 KB: K-quarter partials
    __shared__ float score[TPB][33];      //  4.2 KB: score stash

    const int tid  = threadIdx.x;
    const int lane = tid & 63;
    const int w    = tid >> 6;
    const int wm   = w & 1;           // M-tile (16 tokens)
    const int kq   = w >> 1;          // K-quarter (24 padded k-steps)
    const int tl   = lane & 15;       // token within tile (= B-frag col)
    const int kb   = lane >> 4;       // k sub-block (= frag k group)

    const float* xrow = x + (size_t)(blockIdx.x * TPB + wm * 16 + tl) * HIDDEN + kb * 8;
    const unsigned short* wk = wb + lane * 8;

    f32x4 acc0 = {0.f, 0.f, 0.f, 0.f};   // experts 0..15  x token tl
    f32x4 acc1 = {0.f, 0.f, 0.f, 0.f};   // experts 16..31 x token tl

#define LOADX(A0, A1, sg) do {                                                    \
    const int sx_ = min((sg), 89);                                                \
    A0 = *(const float4*)(xrow + (size_t)sx_ * 32);                               \
    A1 = *(const float4*)(xrow + (size_t)sx_ * 32 + 4);                           \
} while (0)

#define LOADW(W, sg) do {                                                         \
    const unsigned short* p_ = wk + (size_t)min((sg), 95) * 1024;                 \
    W[0] = *(const bf16x8*)(p_);               /* hi,  experts 0-15  */           \
    W[1] = *(const bf16x8*)(p_ + 512);         /* hi,  experts 16-31 */           \
    W[2] = *(const bf16x8*)(p_ + VS);          /* mid, experts 0-15  */           \
    W[3] = *(const bf16x8*)(p_ + VS + 512);    /* mid, experts 16-31 */           \
    W[4] = *(const bf16x8*)(p_ + 2 * VS);      /* lo,  experts 0-15  */           \
    W[5] = *(const bf16x8*)(p_ + 2 * VS + 512);/* lo,  experts 16-31 */           \
} while (0)

#define MFMA12(W, XH, XM, XL) do {                                                \
    acc0 = MFMA(W[0], XH, acc0);                                                  \
    acc1 = MFMA(W[1], XH, acc1);                                                  \
    acc0 = MFMA(W[2], XH, acc0);                                                  \
    acc1 = MFMA(W[3], XH, acc1);                                                  \
    acc0 = MFMA(W[4], XH, acc0);                                                  \
    acc1 = MFMA(W[5], XH, acc1);                                                  \
    acc0 = MFMA(W[0], XM, acc0);                                                  \
    acc1 = MFMA(W[1], XM, acc1);                                                  \
    acc0 = MFMA(W[2], XM, acc0);                                                  \
    acc1 = MFMA(W[3], XM, acc1);                                                  \
    acc0 = MFMA(W[0], XL, acc0);                                                  \
    acc1 = MFMA(W[1], XL, acc1);                                                  \
} while (0)

    const int sg0 = kq * 24;
    float4 xa0, xa1, xb0, xb1;
    bf16x8 Wa[6], Wb[6];
    LOADX(xa0, xa1, sg0);     LOADW(Wa, sg0);
    LOADX(xb0, xb1, sg0 + 1); LOADW(Wb, sg0 + 1);

#pragma unroll 1
    for (int i = 0; i < 12; ++i) {
        const int s = sg0 + 2 * i;
        // phase A (step s)
        {
            bf16x8 xh, xm, xl;
            split24(xa0, xa1, xh, xm, xl);
            LOADX(xa0, xa1, s + 2);           // reload right after consume
            MFMA12(Wa, xh, xm, xl);
            LOADW(Wa, s + 2);
        }
        // phase B (step s+1)
        {
            bf16x8 xh, xm, xl;
            split24(xb0, xb1, xh, xm, xl);
            LOADX(xb0, xb1, s + 3);
            MFMA12(Wb, xh, xm, xl);
            LOADW(Wb, s + 3);
        }
    }

#undef LOADX
#undef LOADW
#undef MFMA12

    // ---- C/D layout (verified r7/r8): col=lane&15=token, row=(lane>>4)*4+j=expert ----
    {
        const int eb = (lane >> 4) * 4;
        *(f32x4*)&part[kq][wm * 16 + tl][eb]      = acc0;
        *(f32x4*)&part[kq][wm * 16 + tl][16 + eb] = acc1;
    }
    __syncthreads();

    // ---- top-4 + softmax, one lane per token ----
    if (tid < TPB) {
        float lg[NE];
#pragma unroll
        for (int e = 0; e < NE; ++e)
            lg[e] = part[0][tid][e] + part[1][tid][e]
                  + part[2][tid][e] + part[3][tid][e] + bias[e];

        float vals[TOPK]; int idxs[TOPK]; unsigned chosen = 0u;
#pragma unroll
        for (int k = 0; k < TOPK; ++k) {
            float m = -INFINITY; int mi = 0;
#pragma unroll
            for (int e = 0; e < NE; ++e) {
                const bool take = (((chosen >> e) & 1u) == 0u) && (lg[e] > m);
                m  = take ? lg[e] : m;
                mi = take ? e : mi;
            }
            vals[k] = m; idxs[k] = mi; chosen |= (1u << (unsigned)mi);
        }
        const float mx = vals[0];
        float p[TOPK]; float sum = 0.f;
#pragma unroll
        for (int k = 0; k < TOPK; ++k) { p[k] = __expf(vals[k] - mx); sum += p[k]; }
        const float inv = 1.0f / sum;
#pragma unroll
        for (int e = 0; e < NE; ++e) {
            float v = 0.f;
#pragma unroll
            for (int k = 0; k < TOPK; ++k) v = (e == idxs[k]) ? p[k] * inv : v;
            score[tid][e] = v;
        }
        const int t = blockIdx.x * TPB + tid;
        float4 iv = make_float4((float)idxs[0], (float)idxs[1], (float)idxs[2], (float)idxs[3]);
        *reinterpret_cast<float4*>(out_idx + (size_t)t * TOPK) = iv;
    }
    __syncthreads();

    // ---- coalesced score store: 1024 floats, 512 threads x float2 ----
    {
        const int f = tid * 2;
        const int t = f >> 5, e = f & 31;
        float2 v = make_float2(score[t][e], score[t][e + 1]);
        *reinterpret_cast<float2*>(out_scores + (size_t)blockIdx.x * TPB * NE + f) = v;
    }
}

extern "C" void kernel_launch(void* const* d_in, const int* in_sizes, int n_in,
                              void* d_out, int out_size, void* d_ws, size_t ws_size,
                              hipStream_t stream)
{
    const float* x = (const float*)d_in[0];
    const float* w = (const float*)d_in[1];
    const float* b = (const float*)d_in[2];
    const int T = in_sizes[0] / HIDDEN;            // 16384 tokens

    unsigned short* wbuf = (unsigned short*)d_ws;  // 3*96*2*512 bf16 = 1.18 MB
    float* out        = (float*)d_out;
    float* out_scores = out;                       // [T, 32]
    float* out_idx    = out + (size_t)T * NE;      // [T, 4] as fp32 values

    wb_kernel<<<dim3((3 * VS + 255) / 256), dim3(256), 0, stream>>>(w, wbuf);
    router_kernel<<<dim3(T / TPB), dim3(512), 0, stream>>>(x, wbuf, b, out_scores, out_idx);
}

// Round 10
// 54.954 us; speedup vs baseline: 1.0215x; 1.0215x over previous
//
#include <hip/hip_runtime.h>
#include <math.h>

// GptOssTopKRouter on MI355X — round 10: 32x32x16 MFMA, operand-swapped
// 3-term split-bf16, no LDS staging, 4 waves/SIMD.
//
// logits^T = W[32,2880] @ X^T as 6 bf16 MFMA passes (wh,wm,wl x xh,xm,xl
// upper-triangle: hh,mh,lh,hm,mm,hl -> logit err ~2e-7, tie-safe top-4).
//
// Round-9 null result (occupancy 2->4/SIMD, same 56us) => W-fragment
// delivery dominates. 32x32x16 fixes it structurally: 32 experts = ONE
// A-tile, 32 tokens = ONE B-tile -> per k16-step just 3 W loads + 2 X
// loads feed 6 MFMAs covering 32 tokens. W instrs/token and MFMA/token
// both halve vs round 9; X unchanged and still register-native:
// B-frag (col=lane&31=token, k=(lane>>5)*8+j) == X row-major slice.
//
// wave = 32 tokens x K-eighth (24 k16-steps; K16 padded 180->192, pad W=0,
// X addr clamped). Block = 8 waves = 8 K-eighths, TPB=32, grid 512 ->
// 2 blocks/CU = 16 waves/CU = 4/SIMD. 2-phase reload-after-consume
// pipeline, zero barriers in the main loop.

#define HIDDEN 2880
#define NE 32
#define TOPK 4
#define TPB 32            // tokens per block
#define NK16 192          // padded k16 steps (180 real + 12 zero)
#define RK16 180          // real k16 steps
#define VS (NK16 * 512)   // ver stride in wb: 98304 shorts

typedef __attribute__((ext_vector_type(8)))  short bf16x8;
typedef __attribute__((ext_vector_type(16))) float f32x16;

#define MFMA32(a, b, c) __builtin_amdgcn_mfma_f32_32x32x16_bf16((a), (b), (c), 0, 0, 0)

// Pre-kernel: W[32][2880] fp32 -> WB[3 ver][192 ks][512] bf16, exact 32x32
// A-fragment order: elem (l,j) = split_ver(W[l&31][ks*16 + (l>>5)*8 + j]);
// ks >= 180 slots are zero.
__global__ void wb_kernel(const float* __restrict__ w, unsigned short* __restrict__ wb) {
    int i = blockIdx.x * 256 + threadIdx.x;
    if (i >= 3 * VS) return;
    int j = i & 7;
    int l = (i >> 3) & 63;
    int rest = i >> 9;
    int ks  = rest % NK16;
    int ver = rest / NK16;
    unsigned short outv = 0;
    if (ks < RK16) {
        int e = l & 31;
        int k = ks * 16 + (l >> 5) * 8 + j;
        float v = w[e * HIDDEN + k];
        unsigned u = __float_as_uint(v);
        unsigned h = u >> 16;
        float r = v - __uint_as_float(u & 0xffff0000u);          // exact
        unsigned ur = __float_as_uint(r);
        unsigned m = ur >> 16;
        float r2 = r - __uint_as_float(ur & 0xffff0000u);        // exact
        unsigned lo = __float_as_uint(r2) >> 16;
        outv = (unsigned short)(ver == 0 ? h : (ver == 1 ? m : lo));
    }
    wb[i] = outv;
}

// split 8 consecutive fp32 -> 3 bf16x8 (hi, mid, lo), fully in-register
__device__ __forceinline__ void split24(float4 a, float4 b,
                                        bf16x8& H, bf16x8& M, bf16x8& L) {
    union { bf16x8 v; unsigned u[4]; } h, m, l;
    float f[8] = {a.x, a.y, a.z, a.w, b.x, b.y, b.z, b.w};
    unsigned hh[8], mm[8], ll[8];
#pragma unroll
    for (int i = 0; i < 8; ++i) {
        unsigned u = __float_as_uint(f[i]);
        hh[i] = u >> 16;
        float r = f[i] - __uint_as_float(u & 0xffff0000u);       // exact
        unsigned ur = __float_as_uint(r);
        mm[i] = ur >> 16;
        float r2 = r - __uint_as_float(ur & 0xffff0000u);        // exact
        ll[i] = __float_as_uint(r2) >> 16;
    }
#pragma unroll
    for (int i = 0; i < 4; ++i) {
        h.u[i] = hh[2 * i] | (hh[2 * i + 1] << 16);
        m.u[i] = mm[2 * i] | (mm[2 * i + 1] << 16);
        l.u[i] = ll[2 * i] | (ll[2 * i + 1] << 16);
    }
    H = h.v; M = m.v; L = l.v;
}

__global__ __launch_bounds__(512, 4)
void router_kernel(const float* __restrict__ x,
                   const unsigned short* __restrict__ wb,
                   const float* __restrict__ bias,
                   float* __restrict__ out_scores,
                   float* __restrict__ out_idx)
{
    __shared__ float part[8][TPB][36];    // 36.9 KB: per-wave K-eighth partials
    __shared__ float score[TPB][33];      //  4.2 KB: score stash

    const int tid  = threadIdx.x;
    const int lane = tid & 63;
    const int w    = tid >> 6;        // K-eighth 0..7
    const int col  = lane & 31;       // token within block (= B-frag col)
    const int kg   = lane >> 5;       // k sub-group (= frag k group)

    const float* xrow = x + (size_t)(blockIdx.x * TPB + col) * HIDDEN + kg * 8;
    const unsigned short* wk = wb + lane * 8;

    f32x16 acc = {0.f};               // 32 experts x token col

#define LOADX(A0, A1, sg) do {                                                    \
    const int sx_ = min((sg), RK16 - 1);                                          \
    A0 = *(const float4*)(xrow + (size_t)sx_ * 16);                               \
    A1 = *(const float4*)(xrow + (size_t)sx_ * 16 + 4);                           \
} while (0)

#define LOADW(W3, sg) do {                                                        \
    const unsigned short* p_ = wk + (size_t)(sg) * 512;                           \
    W3[0] = *(const bf16x8*)(p_);              /* hi  */                          \
    W3[1] = *(const bf16x8*)(p_ + VS);         /* mid */                          \
    W3[2] = *(const bf16x8*)(p_ + 2 * VS);     /* lo  */                          \
} while (0)

#define MFMA6(W3, XH, XM, XL) do {                                                \
    acc = MFMA32(W3[0], XH, acc);                                                 \
    acc = MFMA32(W3[1], XH, acc);                                                 \
    acc = MFMA32(W3[2], XH, acc);                                                 \
    acc = MFMA32(W3[0], XM, acc);                                                 \
    acc = MFMA32(W3[1], XM, acc);                                                 \
    acc = MFMA32(W3[0], XL, acc);                                                 \
} while (0)

    const int sg0 = w * 24;
    float4 xa0, xa1, xb0, xb1;
    bf16x8 Wa[3], Wb[3];
    LOADX(xa0, xa1, sg0);     LOADW(Wa, sg0);
    LOADX(xb0, xb1, sg0 + 1); LOADW(Wb, sg0 + 1);

#pragma unroll 1
    for (int i = 0; i < 12; ++i) {
        const int s = sg0 + 2 * i;
        // phase A (step s)
        {
            bf16x8 xh, xm, xl;
            split24(xa0, xa1, xh, xm, xl);
            if (i < 11) LOADX(xa0, xa1, s + 2);    // reload right after consume
            MFMA6(Wa, xh, xm, xl);
            if (i < 11) LOADW(Wa, s + 2);
        }
        // phase B (step s+1)
        {
            bf16x8 xh, xm, xl;
            split24(xb0, xb1, xh, xm, xl);
            if (i < 11) LOADX(xb0, xb1, s + 3);
            MFMA6(Wb, xh, xm, xl);
            if (i < 11) LOADW(Wb, s + 3);
        }
    }

#undef LOADX
#undef LOADW
#undef MFMA6

    // ---- C/D layout (m74/m101-verified 32x32): col=lane&31=token,
    //      row=(reg&3)+8*(reg>>2)+4*(lane>>5)=expert ----
#pragma unroll
    for (int r = 0; r < 16; ++r)
        part[w][col][(r & 3) + 8 * (r >> 2) + 4 * kg] = acc[r];
    __syncthreads();

    // ---- top-4 + softmax, one lane per token ----
    if (tid < TPB) {
        float lg[NE];
#pragma unroll
        for (int e = 0; e < NE; ++e) {
            float s = bias[e];
#pragma unroll
            for (int p = 0; p < 8; ++p) s += part[p][tid][e];
            lg[e] = s;
        }

        float vals[TOPK]; int idxs[TOPK]; unsigned chosen = 0u;
#pragma unroll
        for (int k = 0; k < TOPK; ++k) {
            float m = -INFINITY; int mi = 0;
#pragma unroll
            for (int e = 0; e < NE; ++e) {
                const bool take = (((chosen >> e) & 1u) == 0u) && (lg[e] > m);
                m  = take ? lg[e] : m;
                mi = take ? e : mi;
            }
            vals[k] = m; idxs[k] = mi; chosen |= (1u << (unsigned)mi);
        }
        const float mx = vals[0];
        float p[TOPK]; float sum = 0.f;
#pragma unroll
        for (int k = 0; k < TOPK; ++k) { p[k] = __expf(vals[k] - mx); sum += p[k]; }
        const float inv = 1.0f / sum;
#pragma unroll
        for (int e = 0; e < NE; ++e) {
            float v = 0.f;
#pragma unroll
            for (int k = 0; k < TOPK; ++k) v = (e == idxs[k]) ? p[k] * inv : v;
            score[tid][e] = v;
        }
        const int t = blockIdx.x * TPB + tid;
        float4 iv = make_float4((float)idxs[0], (float)idxs[1], (float)idxs[2], (float)idxs[3]);
        *reinterpret_cast<float4*>(out_idx + (size_t)t * TOPK) = iv;
    }
    __syncthreads();

    // ---- coalesced score store: 1024 floats, 512 threads x float2 ----
    {
        const int f = tid * 2;
        const int t = f >> 5, e = f & 31;
        float2 v = make_float2(score[t][e], score[t][e + 1]);
        *reinterpret_cast<float2*>(out_scores + (size_t)blockIdx.x * TPB * NE + f) = v;
    }
}

extern "C" void kernel_launch(void* const* d_in, const int* in_sizes, int n_in,
                              void* d_out, int out_size, void* d_ws, size_t ws_size,
                              hipStream_t stream)
{
    const float* x = (const float*)d_in[0];
    const float* w = (const float*)d_in[1];
    const float* b = (const float*)d_in[2];
    const int T = in_sizes[0] / HIDDEN;            // 16384 tokens

    unsigned short* wbuf = (unsigned short*)d_ws;  // 3*192*512 bf16 = 590 KB
    float* out        = (float*)d_out;
    float* out_scores = out;                       // [T, 32]
    float* out_idx    = out + (size_t)T * NE;      // [T, 4] as fp32 values

    wb_kernel<<<dim3((3 * VS + 255) / 256), dim3(256), 0, stream>>>(w, wbuf);
    router_kernel<<<dim3(T / TPB), dim3(512), 0, stream>>>(x, wbuf, b, out_scores, out_idx);
}